// Round 4
// baseline (461.969 us; speedup 1.0000x reference)
//
#include <hip/hip_runtime.h>
#include <hip/hip_bf16.h>
#include <stdint.h>

typedef __bf16 bf16x8 __attribute__((ext_vector_type(8)));
typedef float f32x4 __attribute__((ext_vector_type(4)));

#define XS_BYTES 41472   // 18*18 pixels * 128 B (64ch bf16)

// ---------------- Pass 1: per-block pooled partial sums ----------------
// 1024 blocks x 256 thr; block = 128 KB contiguous fp32 (512 pixels, one b).
__global__ void pool_kernel(const float* __restrict__ x, float* __restrict__ part) {
    __shared__ float red[64];
    const int tid = threadIdx.x;
    if (tid < 64) red[tid] = 0.f;
    __syncthreads();
    const float4* x4 = reinterpret_cast<const float4*>(x) + (size_t)blockIdx.x * 8192;
    float4 s = {0.f, 0.f, 0.f, 0.f};
    #pragma unroll
    for (int i = 0; i < 32; ++i) {
        float4 v = x4[tid + 256 * i];
        s.x += v.x; s.y += v.y; s.z += v.z; s.w += v.w;
    }
    const int c0 = (tid & 15) * 4;
    atomicAdd(&red[c0 + 0], s.x);
    atomicAdd(&red[c0 + 1], s.y);
    atomicAdd(&red[c0 + 2], s.z);
    atomicAdd(&red[c0 + 3], s.w);
    __syncthreads();
    if (tid < 64) part[(size_t)blockIdx.x * 64 + tid] = red[tid];   // no global atomics
}

// ---------------- Pass 2: pooled reduce + MLP + weight aggregation ----------
// grid (32 samples, 9 k-slabs) x 256 thr. Wt[b][f][k] bf16, k=(dh*3+dw)*64+c.
__global__ __launch_bounds__(256)
void wagg_kernel(const float* __restrict__ part, const float* __restrict__ Wk,
                 const float* __restrict__ bk,
                 const float* __restrict__ w1, const float* __restrict__ b1,
                 const float* __restrict__ w2, const float* __restrict__ b2,
                 __hip_bfloat16* __restrict__ Wt, float* __restrict__ bagg) {
    const int b = blockIdx.x, j = blockIdx.y, tid = threadIdx.x;
    __shared__ float accs[64][64];
    __shared__ float psum[4][64];
    __shared__ float pool_sh[64], hsh[16], lg[4], pish[4];

    // issue coalesced Wk slab loads first (overlap with pi computation)
    const int f4 = (tid & 15) * 4;
    const int kr = tid >> 4;
    float4 v[4][4];
    #pragma unroll
    for (int pass = 0; pass < 4; ++pass) {
        const int k = j * 64 + pass * 16 + kr;
        #pragma unroll
        for (int kk = 0; kk < 4; ++kk)
            v[pass][kk] = *reinterpret_cast<const float4*>(Wk + (size_t)kk * 36864 + k * 64 + f4);
    }
    // reduce pooled partials (32 rows per sample)
    {
        const int c = tid & 63, qq = tid >> 6;
        float s = 0.f;
        #pragma unroll
        for (int r = 0; r < 8; ++r) s += part[((size_t)b * 32 + qq * 8 + r) * 64 + c];
        psum[qq][c] = s;
    }
    __syncthreads();
    if (tid < 64)
        pool_sh[tid] = (psum[0][tid] + psum[1][tid] + psum[2][tid] + psum[3][tid]) * (1.f / 16384.f);
    __syncthreads();
    if (tid < 16) {
        float a = 0.f;
        for (int c = 0; c < 64; ++c) a += pool_sh[c] * w1[c * 16 + tid];
        hsh[tid] = fmaxf(a + b1[tid], 0.f);
    }
    __syncthreads();
    if (tid < 4) {
        float a = 0.f;
        for (int jj = 0; jj < 16; ++jj) a += hsh[jj] * w2[jj * 4 + tid];
        lg[tid] = (a + b2[tid]) * (1.f / 30.f);
    }
    __syncthreads();
    if (tid == 0) {
        float m = fmaxf(fmaxf(lg[0], lg[1]), fmaxf(lg[2], lg[3]));
        float e0 = expf(lg[0] - m), e1 = expf(lg[1] - m), e2 = expf(lg[2] - m), e3 = expf(lg[3] - m);
        float inv = 1.f / (e0 + e1 + e2 + e3);
        pish[0] = e0 * inv; pish[1] = e1 * inv; pish[2] = e2 * inv; pish[3] = e3 * inv;
    }
    __syncthreads();
    const float p0 = pish[0], p1 = pish[1], p2 = pish[2], p3 = pish[3];
    #pragma unroll
    for (int pass = 0; pass < 4; ++pass) {
        float4 a;
        a.x = p0*v[pass][0].x + p1*v[pass][1].x + p2*v[pass][2].x + p3*v[pass][3].x;
        a.y = p0*v[pass][0].y + p1*v[pass][1].y + p2*v[pass][2].y + p3*v[pass][3].y;
        a.z = p0*v[pass][0].z + p1*v[pass][1].z + p2*v[pass][2].z + p3*v[pass][3].z;
        a.w = p0*v[pass][0].w + p1*v[pass][1].w + p2*v[pass][2].w + p3*v[pass][3].w;
        *reinterpret_cast<float4*>(&accs[pass * 16 + kr][f4]) = a;
    }
    __syncthreads();
    const int f = tid & 63;
    const int kgo0 = (tid >> 6) * 2;
    #pragma unroll
    for (int t2 = 0; t2 < 2; ++t2) {
        const int kgo = kgo0 + t2;
        bf16x8 o;
        #pragma unroll
        for (int i = 0; i < 8; ++i) o[i] = (__bf16)accs[kgo * 8 + i][f];
        *reinterpret_cast<bf16x8*>(Wt + (size_t)b * 36864 + f * 576 + (j * 8 + kgo) * 8) = o;
    }
    if (j == 0 && tid < 64)
        bagg[b * 64 + tid] = p0*bk[tid] + p1*bk[64+tid] + p2*bk[128+tid] + p3*bk[192+tid];
}

// ---------------- Pass 3: conv ----------------
// 256 blocks x 512 thr (8 waves, 2/SIMD). Block = (b, 16-row stripe), 8 tiles 16x16.
// Wave w: wm=w>>1 -> pixel rows wm*4..+3 (mf=4 frags), wn=w&1 -> F-half (nf=2, B in regs).
// LDS: 2 x [18][18] pixels x 128 B bf16, swizzle byte ^= ((pix&7)<<4).

template<int S>
__device__ __forceinline__ void cstep(const char* bufb, int wm, int l15, int q,
                                      const bf16x8 (&Bf)[2][18], f32x4 (&acc)[4][2]) {
    constexpr int tap = S >> 1, half = S & 1;
    constexpr int dh = tap / 3, dw = tap % 3;
    #pragma unroll
    for (int mf = 0; mf < 4; ++mf) {
        const int r = wm * 4 + mf + dh;
        const int c = l15 + dw;
        const int pix = r * 18 + c;
        const int off = ((pix * 8 + half * 4 + q) << 4) ^ ((pix & 7) << 4);
        const bf16x8 af = *reinterpret_cast<const bf16x8*>(bufb + off);
        acc[mf][0] = __builtin_amdgcn_mfma_f32_16x16x32_bf16(af, Bf[0][S], acc[mf][0], 0, 0, 0);
        acc[mf][1] = __builtin_amdgcn_mfma_f32_16x16x32_bf16(af, Bf[1][S], acc[mf][1], 0, 0, 0);
    }
}

template<int S0, int S1>
__device__ __forceinline__ void crange(const char* bufb, int wm, int l15, int q,
                                       const bf16x8 (&Bf)[2][18], f32x4 (&acc)[4][2]) {
    if constexpr (S0 < S1) {
        cstep<S0>(bufb, wm, l15, q, Bf, acc);
        crange<S0 + 1, S1>(bufb, wm, l15, q, Bf, acc);
    }
}

__global__ __launch_bounds__(512, 2)
void conv_kernel(const float* __restrict__ x, const __hip_bfloat16* __restrict__ Wt,
                 const float* __restrict__ bagg, float* __restrict__ out) {
    extern __shared__ char smem[];
    const int tid  = threadIdx.x;
    const int b    = blockIdx.x >> 3;
    const int th   = blockIdx.x & 7;
    const int lane = tid & 63;
    const int w    = tid >> 6;
    const int wm   = w >> 1;
    const int wn   = w & 1;
    const int l15  = lane & 15;
    const int q    = lane >> 4;

    // ---- B fragments into registers: 2 nf x 18 ks x 4 VGPR = 144 ----
    bf16x8 Bf[2][18];
    {
        const __hip_bfloat16* Wb = Wt + (size_t)b * 36864;
        #pragma unroll
        for (int nf = 0; nf < 2; ++nf) {
            const __hip_bfloat16* fp = Wb + (wn * 32 + nf * 16 + l15) * 576 + q * 8;
            #pragma unroll
            for (int s = 0; s < 18; ++s)
                Bf[nf][s] = *reinterpret_cast<const bf16x8*>(fp + s * 32);
        }
    }
    float bagg_v[2];
    #pragma unroll
    for (int nf = 0; nf < 2; ++nf) bagg_v[nf] = bagg[b * 64 + wn * 32 + nf * 16 + l15];

    const size_t xb = (size_t)b * (128 * 128 * 64);
    const int h0 = th * 16 - 1;

    float4 svA[3][2], svB[3][2];

    // issue global fp32 loads for half the tile (granule = 8ch bf16 dest, 32B src)
    auto sload = [&](int tw, float4 (&sv)[3][2], int i0) {
        const int w0 = tw * 16 - 1;
        #pragma unroll
        for (int i = 0; i < 3; ++i) {
            const int g = (i0 + i) * 512 + tid;
            float4 va = {0.f,0.f,0.f,0.f}, vb = {0.f,0.f,0.f,0.f};
            if (g < 2592) {
                const int pix = g >> 3;
                const int r = pix / 18;
                const int c = pix - r * 18;
                const int gh = h0 + r, gw = w0 + c;
                if ((unsigned)gh < 128u && (unsigned)gw < 128u) {
                    const float* src = x + xb + ((size_t)(gh * 128 + gw) * 64 + (g & 7) * 8);
                    va = *reinterpret_cast<const float4*>(src);
                    vb = *reinterpret_cast<const float4*>(src + 4);
                }
            }
            sv[i][0] = va; sv[i][1] = vb;
        }
    };
    // convert + swizzled ds_write (compiler inserts the vmcnt waits)
    auto swrite = [&](int buf, float4 (&sv)[3][2], int i0) {
        char* bufb = smem + buf * XS_BYTES;
        #pragma unroll
        for (int i = 0; i < 3; ++i) {
            const int g = (i0 + i) * 512 + tid;
            if (g < 2592) {
                bf16x8 o;
                o[0] = (__bf16)sv[i][0].x; o[1] = (__bf16)sv[i][0].y;
                o[2] = (__bf16)sv[i][0].z; o[3] = (__bf16)sv[i][0].w;
                o[4] = (__bf16)sv[i][1].x; o[5] = (__bf16)sv[i][1].y;
                o[6] = (__bf16)sv[i][1].z; o[7] = (__bf16)sv[i][1].w;
                const int off = (g << 4) ^ (((g >> 3) & 7) << 4);
                *reinterpret_cast<bf16x8*>(bufb + off) = o;
            }
        }
    };

    // prologue: tile 0 into buf 0
    sload(0, svA, 0);
    sload(0, svB, 3);
    swrite(0, svA, 0);
    swrite(0, svB, 3);

    #pragma unroll 1
    for (int tw = 0; tw < 8; ++tw) {
        __syncthreads();                        // buf[tw&1] ready for all waves
        const char* bufb = smem + (tw & 1) * XS_BYTES;
        const int nxt = (tw + 1) & 1;

        f32x4 acc[4][2];
        #pragma unroll
        for (int mf = 0; mf < 4; ++mf) {
            acc[mf][0] = (f32x4){0.f, 0.f, 0.f, 0.f};
            acc[mf][1] = (f32x4){0.f, 0.f, 0.f, 0.f};
        }

        if (tw < 7) sload(tw + 1, svA, 0);      // issue early (hide under MFMA)
        crange<0, 9>(bufb, wm, l15, q, Bf, acc);
        if (tw < 7) { swrite(nxt, svA, 0); sload(tw + 1, svB, 3); }
        crange<9, 18>(bufb, wm, l15, q, Bf, acc);
        if (tw < 7) swrite(nxt, svB, 3);

        // epilogue: C row = q*4+j (pixel col), C col = l15 (f)
        #pragma unroll
        for (int mf = 0; mf < 4; ++mf) {
            const int hh = th * 16 + wm * 4 + mf;
            float* rowp = out + (((size_t)b * 128 + hh) * 128 + tw * 16) * 64 + wn * 32 + l15;
            #pragma unroll
            for (int j = 0; j < 4; ++j) {
                const int ww = q * 4 + j;
                rowp[(size_t)ww * 64]      = acc[mf][0][j] + bagg_v[0];
                rowp[(size_t)ww * 64 + 16] = acc[mf][1][j] + bagg_v[1];
            }
        }
    }
}

extern "C" void kernel_launch(void* const* d_in, const int* in_sizes, int n_in,
                              void* d_out, int out_size, void* d_ws, size_t ws_size,
                              hipStream_t stream) {
    const float* x   = (const float*)d_in[0];
    const float* Wk  = (const float*)d_in[1];
    const float* bk  = (const float*)d_in[2];
    const float* w1  = (const float*)d_in[3];
    const float* b1  = (const float*)d_in[4];
    const float* w2  = (const float*)d_in[5];
    const float* b2  = (const float*)d_in[6];
    float* out = (float*)d_out;

    char* ws = (char*)d_ws;
    float* part = (float*)ws;                           // 1024*64*4 = 256 KB
    float* bagg = (float*)(ws + 262144);                // 8 KB
    __hip_bfloat16* Wt = (__hip_bfloat16*)(ws + 270336); // 2.25 MB

    pool_kernel<<<1024, 256, 0, stream>>>(x, part);
    wagg_kernel<<<dim3(32, 9), 256, 0, stream>>>(part, Wk, bk, w1, b1, w2, b2, Wt, bagg);

    static bool attr_set = false;
    if (!attr_set) {
        hipFuncSetAttribute((const void*)conv_kernel,
                            hipFuncAttributeMaxDynamicSharedMemorySize, 2 * XS_BYTES);
        attr_set = true;
    }
    conv_kernel<<<256, 512, 2 * XS_BYTES, stream>>>(x, Wt, bagg, out);
}

// Round 5
// 302.476 us; speedup vs baseline: 1.5273x; 1.5273x over previous
//
#include <hip/hip_runtime.h>
#include <hip/hip_bf16.h>
#include <stdint.h>

typedef __bf16 bf16x8 __attribute__((ext_vector_type(8)));
typedef float f32x4 __attribute__((ext_vector_type(4)));

#define XS_BYTES 41472   // 18*18 pixels * 128 B (64ch bf16)

// ---------------- Pass 1: per-block pooled partial sums ----------------
__global__ void pool_kernel(const float* __restrict__ x, float* __restrict__ part) {
    __shared__ float red[64];
    const int tid = threadIdx.x;
    if (tid < 64) red[tid] = 0.f;
    __syncthreads();
    const float4* x4 = reinterpret_cast<const float4*>(x) + (size_t)blockIdx.x * 8192;
    float4 s = {0.f, 0.f, 0.f, 0.f};
    #pragma unroll
    for (int i = 0; i < 32; ++i) {
        float4 v = x4[tid + 256 * i];
        s.x += v.x; s.y += v.y; s.z += v.z; s.w += v.w;
    }
    const int c0 = (tid & 15) * 4;
    atomicAdd(&red[c0 + 0], s.x);
    atomicAdd(&red[c0 + 1], s.y);
    atomicAdd(&red[c0 + 2], s.z);
    atomicAdd(&red[c0 + 3], s.w);
    __syncthreads();
    if (tid < 64) part[(size_t)blockIdx.x * 64 + tid] = red[tid];
}

// ---------------- Pass 2: pooled reduce + MLP + weight aggregation ----------
__global__ __launch_bounds__(256)
void wagg_kernel(const float* __restrict__ part, const float* __restrict__ Wk,
                 const float* __restrict__ bk,
                 const float* __restrict__ w1, const float* __restrict__ b1,
                 const float* __restrict__ w2, const float* __restrict__ b2,
                 __hip_bfloat16* __restrict__ Wt, float* __restrict__ bagg) {
    const int b = blockIdx.x, j = blockIdx.y, tid = threadIdx.x;
    __shared__ float accs[64][64];
    __shared__ float psum[4][64];
    __shared__ float pool_sh[64], hsh[16], lg[4], pish[4];

    const int f4 = (tid & 15) * 4;
    const int kr = tid >> 4;
    float4 v[4][4];
    #pragma unroll
    for (int pass = 0; pass < 4; ++pass) {
        const int k = j * 64 + pass * 16 + kr;
        #pragma unroll
        for (int kk = 0; kk < 4; ++kk)
            v[pass][kk] = *reinterpret_cast<const float4*>(Wk + (size_t)kk * 36864 + k * 64 + f4);
    }
    {
        const int c = tid & 63, qq = tid >> 6;
        float s = 0.f;
        #pragma unroll
        for (int r = 0; r < 8; ++r) s += part[((size_t)b * 32 + qq * 8 + r) * 64 + c];
        psum[qq][c] = s;
    }
    __syncthreads();
    if (tid < 64)
        pool_sh[tid] = (psum[0][tid] + psum[1][tid] + psum[2][tid] + psum[3][tid]) * (1.f / 16384.f);
    __syncthreads();
    if (tid < 16) {
        float a = 0.f;
        for (int c = 0; c < 64; ++c) a += pool_sh[c] * w1[c * 16 + tid];
        hsh[tid] = fmaxf(a + b1[tid], 0.f);
    }
    __syncthreads();
    if (tid < 4) {
        float a = 0.f;
        for (int jj = 0; jj < 16; ++jj) a += hsh[jj] * w2[jj * 4 + tid];
        lg[tid] = (a + b2[tid]) * (1.f / 30.f);
    }
    __syncthreads();
    if (tid == 0) {
        float m = fmaxf(fmaxf(lg[0], lg[1]), fmaxf(lg[2], lg[3]));
        float e0 = expf(lg[0] - m), e1 = expf(lg[1] - m), e2 = expf(lg[2] - m), e3 = expf(lg[3] - m);
        float inv = 1.f / (e0 + e1 + e2 + e3);
        pish[0] = e0 * inv; pish[1] = e1 * inv; pish[2] = e2 * inv; pish[3] = e3 * inv;
    }
    __syncthreads();
    const float p0 = pish[0], p1 = pish[1], p2 = pish[2], p3 = pish[3];
    #pragma unroll
    for (int pass = 0; pass < 4; ++pass) {
        float4 a;
        a.x = p0*v[pass][0].x + p1*v[pass][1].x + p2*v[pass][2].x + p3*v[pass][3].x;
        a.y = p0*v[pass][0].y + p1*v[pass][1].y + p2*v[pass][2].y + p3*v[pass][3].y;
        a.z = p0*v[pass][0].z + p1*v[pass][1].z + p2*v[pass][2].z + p3*v[pass][3].z;
        a.w = p0*v[pass][0].w + p1*v[pass][1].w + p2*v[pass][2].w + p3*v[pass][3].w;
        *reinterpret_cast<float4*>(&accs[pass * 16 + kr][f4]) = a;
    }
    __syncthreads();
    const int f = tid & 63;
    const int kgo0 = (tid >> 6) * 2;
    #pragma unroll
    for (int t2 = 0; t2 < 2; ++t2) {
        const int kgo = kgo0 + t2;
        bf16x8 o;
        #pragma unroll
        for (int i = 0; i < 8; ++i) o[i] = (__bf16)accs[kgo * 8 + i][f];
        *reinterpret_cast<bf16x8*>(Wt + (size_t)b * 36864 + f * 576 + (j * 8 + kgo) * 8) = o;
    }
    if (j == 0 && tid < 64)
        bagg[b * 64 + tid] = p0*bk[tid] + p1*bk[64+tid] + p2*bk[128+tid] + p3*bk[192+tid];
}

// ---------------- Pass 3: conv ----------------
// 256 blocks x 256 thr (4 waves, 1/SIMD, 512-VGPR budget -> no spills).
// Block = (b, 16-row stripe th); 8 tiles of 16x16 px.
// Wave w: wm=w>>1 (row-half: 8 rows, mf=0..7), wn=w&1 (F-half, nf=0..1).
// B weights in registers: Bf[2][18] = 144 VGPRs/wave.
// LDS: 2 x [18][18] px x 128 B bf16, swizzle byte ^= ((pix&7)<<4)  (measured 0-conflict).
// K-loop with dh-reuse: per (dw,half) read 10 row-frags, fire 48 MFMAs.

template<int DW>
__device__ __forceinline__ void cdw(const char* bufb, int wm, int l15, int q,
                                    const bf16x8 (&Bf)[2][18], f32x4 (&acc)[8][2]) {
    #pragma unroll
    for (int half = 0; half < 2; ++half) {
        bf16x8 ar[10];
        #pragma unroll
        for (int jr = 0; jr < 10; ++jr) {
            const int pix = (wm * 8 + jr) * 18 + l15 + DW;
            const int off = ((pix * 8 + half * 4 + q) << 4) ^ ((pix & 7) << 4);
            ar[jr] = *reinterpret_cast<const bf16x8*>(bufb + off);
        }
        #pragma unroll
        for (int dh = 0; dh < 3; ++dh) {
            const int s = (dh * 3 + DW) * 2 + half;   // compile-time
            #pragma unroll
            for (int mf = 0; mf < 8; ++mf) {
                acc[mf][0] = __builtin_amdgcn_mfma_f32_16x16x32_bf16(ar[mf + dh], Bf[0][s], acc[mf][0], 0, 0, 0);
                acc[mf][1] = __builtin_amdgcn_mfma_f32_16x16x32_bf16(ar[mf + dh], Bf[1][s], acc[mf][1], 0, 0, 0);
            }
        }
    }
}

__global__ __launch_bounds__(256, 1)
void conv_kernel(const float* __restrict__ x, const __hip_bfloat16* __restrict__ Wt,
                 const float* __restrict__ bagg, float* __restrict__ out) {
    extern __shared__ char smem[];
    const int tid  = threadIdx.x;
    const int b    = blockIdx.x >> 3;
    const int th   = blockIdx.x & 7;
    const int lane = tid & 63;
    const int w    = tid >> 6;
    const int wm   = w >> 1;
    const int wn   = w & 1;
    const int l15  = lane & 15;
    const int q    = lane >> 4;

    // ---- B fragments into registers/AGPRs: 2 x 18 x 4 = 144 ----
    bf16x8 Bf[2][18];
    {
        const __hip_bfloat16* Wb = Wt + (size_t)b * 36864;
        #pragma unroll
        for (int nf = 0; nf < 2; ++nf) {
            const __hip_bfloat16* fp = Wb + (wn * 32 + nf * 16 + l15) * 576 + q * 8;
            #pragma unroll
            for (int s = 0; s < 18; ++s)
                Bf[nf][s] = *reinterpret_cast<const bf16x8*>(fp + s * 32);
        }
    }
    float bagg_v[2];
    #pragma unroll
    for (int nf = 0; nf < 2; ++nf) bagg_v[nf] = bagg[b * 64 + wn * 32 + nf * 16 + l15];

    const size_t xb = (size_t)b * (128 * 128 * 64);
    const int h0 = th * 16 - 1;

    float4 svA[5][2], svB[6][2];

    auto sloadA = [&](int tw) {
        const int w0 = tw * 16 - 1;
        #pragma unroll
        for (int i = 0; i < 5; ++i) {
            const int g = i * 256 + tid;
            const int pix = g >> 3;
            const int r = pix / 18, c = pix - r * 18;
            const int gh = h0 + r, gw = w0 + c;
            float4 va = {0.f,0.f,0.f,0.f}, vb = {0.f,0.f,0.f,0.f};
            if ((unsigned)gh < 128u && (unsigned)gw < 128u) {
                const float* src = x + xb + ((size_t)(gh * 128 + gw) * 64 + (g & 7) * 8);
                va = *reinterpret_cast<const float4*>(src);
                vb = *reinterpret_cast<const float4*>(src + 4);
            }
            svA[i][0] = va; svA[i][1] = vb;
        }
    };
    auto sloadB = [&](int tw) {
        const int w0 = tw * 16 - 1;
        #pragma unroll
        for (int i = 0; i < 6; ++i) {
            const int g = (5 + i) * 256 + tid;
            float4 va = {0.f,0.f,0.f,0.f}, vb = {0.f,0.f,0.f,0.f};
            if (g < 2592) {
                const int pix = g >> 3;
                const int r = pix / 18, c = pix - r * 18;
                const int gh = h0 + r, gw = w0 + c;
                if ((unsigned)gh < 128u && (unsigned)gw < 128u) {
                    const float* src = x + xb + ((size_t)(gh * 128 + gw) * 64 + (g & 7) * 8);
                    va = *reinterpret_cast<const float4*>(src);
                    vb = *reinterpret_cast<const float4*>(src + 4);
                }
            }
            svB[i][0] = va; svB[i][1] = vb;
        }
    };
    auto swriteA = [&](int buf) {
        char* bufb = smem + buf * XS_BYTES;
        #pragma unroll
        for (int i = 0; i < 5; ++i) {
            const int g = i * 256 + tid;
            bf16x8 o;
            o[0] = (__bf16)svA[i][0].x; o[1] = (__bf16)svA[i][0].y;
            o[2] = (__bf16)svA[i][0].z; o[3] = (__bf16)svA[i][0].w;
            o[4] = (__bf16)svA[i][1].x; o[5] = (__bf16)svA[i][1].y;
            o[6] = (__bf16)svA[i][1].z; o[7] = (__bf16)svA[i][1].w;
            const int off = (g << 4) ^ (((g >> 3) & 7) << 4);
            *reinterpret_cast<bf16x8*>(bufb + off) = o;
        }
    };
    auto swriteB = [&](int buf) {
        char* bufb = smem + buf * XS_BYTES;
        #pragma unroll
        for (int i = 0; i < 6; ++i) {
            const int g = (5 + i) * 256 + tid;
            if (g < 2592) {
                bf16x8 o;
                o[0] = (__bf16)svB[i][0].x; o[1] = (__bf16)svB[i][0].y;
                o[2] = (__bf16)svB[i][0].z; o[3] = (__bf16)svB[i][0].w;
                o[4] = (__bf16)svB[i][1].x; o[5] = (__bf16)svB[i][1].y;
                o[6] = (__bf16)svB[i][1].z; o[7] = (__bf16)svB[i][1].w;
                const int off = (g << 4) ^ (((g >> 3) & 7) << 4);
                *reinterpret_cast<bf16x8*>(bufb + off) = o;
            }
        }
    };

    // prologue: tile 0 -> buf 0
    sloadA(0); sloadB(0); swriteA(0); swriteB(0);

    #pragma unroll 1
    for (int tw = 0; tw < 8; ++tw) {
        __syncthreads();                       // buf[tw&1] ready; buf[nxt] free
        const char* bufb = smem + (tw & 1) * XS_BYTES;
        const int nxt = (tw + 1) & 1;

        f32x4 acc[8][2];
        #pragma unroll
        for (int mf = 0; mf < 8; ++mf) {
            acc[mf][0] = (f32x4){0.f, 0.f, 0.f, 0.f};
            acc[mf][1] = (f32x4){0.f, 0.f, 0.f, 0.f};
        }

        if (tw < 7) { sloadA(tw + 1); sloadB(tw + 1); }   // issue loads early
        cdw<0>(bufb, wm, l15, q, Bf, acc);
        if (tw < 7) swriteA(nxt);                          // waits svA vmcnt
        cdw<1>(bufb, wm, l15, q, Bf, acc);
        if (tw < 7) swriteB(nxt);
        cdw<2>(bufb, wm, l15, q, Bf, acc);

        // epilogue: C row = q*4+jj (pixel col), C col = l15 (f)
        #pragma unroll
        for (int mf = 0; mf < 8; ++mf) {
            const int hh = th * 16 + wm * 8 + mf;
            float* rowp = out + (((size_t)b * 128 + hh) * 128 + tw * 16) * 64 + wn * 32 + l15;
            #pragma unroll
            for (int jj = 0; jj < 4; ++jj) {
                const int ww = q * 4 + jj;
                rowp[(size_t)ww * 64]      = acc[mf][0][jj] + bagg_v[0];
                rowp[(size_t)ww * 64 + 16] = acc[mf][1][jj] + bagg_v[1];
            }
        }
    }
}

extern "C" void kernel_launch(void* const* d_in, const int* in_sizes, int n_in,
                              void* d_out, int out_size, void* d_ws, size_t ws_size,
                              hipStream_t stream) {
    const float* x   = (const float*)d_in[0];
    const float* Wk  = (const float*)d_in[1];
    const float* bk  = (const float*)d_in[2];
    const float* w1  = (const float*)d_in[3];
    const float* b1  = (const float*)d_in[4];
    const float* w2  = (const float*)d_in[5];
    const float* b2  = (const float*)d_in[6];
    float* out = (float*)d_out;

    char* ws = (char*)d_ws;
    float* part = (float*)ws;                            // 256 KB
    float* bagg = (float*)(ws + 262144);                 // 8 KB
    __hip_bfloat16* Wt = (__hip_bfloat16*)(ws + 270336); // 2.25 MB

    pool_kernel<<<1024, 256, 0, stream>>>(x, part);
    wagg_kernel<<<dim3(32, 9), 256, 0, stream>>>(part, Wk, bk, w1, b1, w2, b2, Wt, bagg);

    static bool attr_set = false;
    if (!attr_set) {
        hipFuncSetAttribute((const void*)conv_kernel,
                            hipFuncAttributeMaxDynamicSharedMemorySize, 2 * XS_BYTES);
        attr_set = true;
    }
    conv_kernel<<<256, 256, 2 * XS_BYTES, stream>>>(x, Wt, bagg, out);
}